// Round 10
// baseline (521.747 us; speedup 1.0000x reference)
//
#include <hip/hip_runtime.h>
#include <hip/hip_bf16.h>
#include <hip/hip_cooperative_groups.h>
#include <cstddef>

namespace cg = cooperative_groups;

// ---------------------------------------------------------------------------
// 2-layer GCN, single cooperative mega-kernel (R23).
// History: R15 171.2 (best multi-kernel); R17/R19/R22 neutral; R18/R20
// regressed (feature chunking: +5-6us VALU/pass, 64B chunks alias 128B
// lines); R21 failed (W1f produced+consumed in same dispatch). Sum of
// per-kernel work ~100us vs 171 total across 5 different layouts ->
// ~60-70us lives BETWEEN dispatches. R23 fuses everything with grid.sync:
//  A: deg/lb zero + W1/W2 -> MFMA-B fragment order
//  B: count (rank from atomicAdd return)
//  C: scan (blocks 0..SB-1) || gemm1 unscaled (blocks SB.., needs only W1f)
//  D: fill (no atomics)
//  E: aggmm w/ per-edge dinv[s] weight via coalesced csr+dinv preload + shfl
//     broadcast (R22-verified math), h2 written dinv-folded
//  F: aggout (unit weights, h2 pre-folded)
// ---------------------------------------------------------------------------

typedef __attribute__((ext_vector_type(8))) short short8;
typedef __attribute__((ext_vector_type(4))) float f32x4;
typedef unsigned long long u64;

__device__ inline unsigned short f2bf(float f) {
    __hip_bfloat16 b = __float2bfloat16(f);
    return *reinterpret_cast<unsigned short*>(&b);
}
__device__ inline float bf2f_lo(unsigned int u) {
    unsigned int v = u << 16;
    return *reinterpret_cast<float*>(&v);
}
__device__ inline float bf2f_hi(unsigned int u) {
    unsigned int v = u & 0xffff0000u;
    return *reinterpret_cast<float*>(&v);
}
__device__ inline u64 ld_acq64(u64* p) {
    return __hip_atomic_load(p, __ATOMIC_ACQUIRE, __HIP_MEMORY_SCOPE_AGENT);
}
__device__ inline void st_rel64(u64* p, u64 v) {
    __hip_atomic_store(p, v, __ATOMIC_RELEASE, __HIP_MEMORY_SCOPE_AGENT);
}

__global__ __launch_bounds__(256, 4) void fused_kernel(
    const int* __restrict__ src, const int* __restrict__ dst, int E,
    int* __restrict__ deg, unsigned short* __restrict__ rank,
    const float* __restrict__ W1, const float* __restrict__ W2,
    unsigned short* __restrict__ W1f, unsigned short* __restrict__ W2f,
    u64* __restrict__ lb,
    const float* __restrict__ x, unsigned short* __restrict__ h1,
    int* __restrict__ offs, float* __restrict__ dinv,
    int* __restrict__ csr,
    const float* __restrict__ b1, const float* __restrict__ b2,
    unsigned short* __restrict__ h2, float* __restrict__ out,
    int N, int CB, int SB, int GB, int AT, int OT) {

    cg::grid_group grid = cg::this_grid();
    int b = blockIdx.x;
    int NB = gridDim.x;
    int tid = threadIdx.x;

    __shared__ unsigned short As[64 * 128];  // 16 KB, reused by gemm1/aggmm
    __shared__ int ws[4];
    __shared__ int s_prefix;

    // ================= A: init (deg zero, W-frag, lb zero) =================
    {
        for (int gi = b * 256 + tid; gi < N; gi += NB * 256) deg[gi] = 0;
        int gi = b * 256 + tid;
        if (gi < 64) lb[gi] = 0;
        if (gi < 3072) {
            const float* W;
            unsigned short* Wf;
            int n, oct, Nc;
            if (gi < 2048) { W = W1; Wf = W1f; Nc = 128; n = gi >> 4; oct = gi & 15; }
            else { W = W2; Wf = W2f; Nc = 64; int i2 = gi - 2048; n = i2 >> 4; oct = i2 & 15; }
            int k0 = oct * 8;
            int ks = k0 >> 5, quad = (k0 >> 3) & 3, ntg = n >> 4;
            short8 v;
            #pragma unroll
            for (int j = 0; j < 8; j++) v[j] = (short)f2bf(W[(k0 + j) * Nc + n]);
            int off = (((ntg * 4 + ks) * 64) + (n & 15) + 16 * quad) * 8;
            *(short8*)(Wf + off) = v;
        }
    }
    grid.sync();

    // ================= B: count (4 edges/thread, rank capture) =============
    for (int u = b; u < CB; u += NB) {
        int i = (u * 256 + tid) * 4;
        if (i + 3 < E) {
            int4 d = *(const int4*)(dst + i);
            unsigned short r0 = (unsigned short)atomicAdd(&deg[d.x], 1);
            unsigned short r1 = (unsigned short)atomicAdd(&deg[d.y], 1);
            unsigned short r2 = (unsigned short)atomicAdd(&deg[d.z], 1);
            unsigned short r3 = (unsigned short)atomicAdd(&deg[d.w], 1);
            *(ushort4*)(rank + i) = make_ushort4(r0, r1, r2, r3);
        } else {
            for (; i < E; i++) rank[i] = (unsigned short)atomicAdd(&deg[dst[i]], 1);
        }
    }
    grid.sync();

    // ========== C: scan (blocks 0..SB-1)  ||  gemm1 (blocks SB..) ==========
    if (b < SB) {
        int sb = b;
        int lane = tid & 63;
        int wv = tid >> 6;
        int i = sb * 1024 + tid * 4;
        int v0 = (i + 0 < N) ? deg[i + 0] : 0;
        int v1 = (i + 1 < N) ? deg[i + 1] : 0;
        int v2 = (i + 2 < N) ? deg[i + 2] : 0;
        int v3 = (i + 3 < N) ? deg[i + 3] : 0;
        int tsum = v0 + v1 + v2 + v3;
        int xs = tsum;
        #pragma unroll
        for (int off = 1; off < 64; off <<= 1) {
            int y = __shfl_up(xs, off, 64);
            if (lane >= off) xs += y;
        }
        if (lane == 63) ws[wv] = xs;
        __syncthreads();
        int wprefix = 0;
        #pragma unroll
        for (int w2 = 0; w2 < 4; w2++) wprefix += (w2 < wv) ? ws[w2] : 0;
        int chunk_total = ws[0] + ws[1] + ws[2] + ws[3];

        if (wv == 0) {
            if (lane == 0)
                st_rel64(&lb[sb], ((u64)(unsigned)chunk_total << 2) | 1ull);
            int contrib = 0;
            if (sb > 0) {
                int pred = sb - 1 - lane;
                for (;;) {
                    u64 v = (pred >= 0) ? ld_acq64(&lb[pred]) : 2ull;
                    int flag = (int)(v & 3);
                    u64 ball2 = __ballot(flag == 2);
                    u64 ball0 = __ballot(flag == 0);
                    if (ball2 != 0) {
                        int L = __ffsll(ball2) - 1;
                        if ((ball0 & ((1ull << L) - 1)) == 0) {
                            contrib = (lane <= L) ? (int)(unsigned)(v >> 2) : 0;
                            break;
                        }
                    }
                    __builtin_amdgcn_s_sleep(1);
                }
                #pragma unroll
                for (int off = 32; off >= 1; off >>= 1)
                    contrib += __shfl_xor(contrib, off, 64);
            }
            if (lane == 0) {
                st_rel64(&lb[sb], ((u64)(unsigned)(contrib + chunk_total) << 2) | 2ull);
                s_prefix = contrib;
            }
        }
        __syncthreads();

        int carry = s_prefix;
        int e0 = carry + wprefix + xs - tsum;
        int e1 = e0 + v0, e2 = e1 + v1, e3 = e2 + v2;
        if (i + 0 < N) { offs[i + 0] = e0; dinv[i + 0] = rsqrtf((float)(v0 + 1)); }
        if (i + 1 < N) { offs[i + 1] = e1; dinv[i + 1] = rsqrtf((float)(v1 + 1)); }
        if (i + 2 < N) { offs[i + 2] = e2; dinv[i + 2] = rsqrtf((float)(v2 + 1)); }
        if (i + 3 < N) { offs[i + 3] = e3; dinv[i + 3] = rsqrtf((float)(v3 + 1)); }
        if (sb == SB - 1 && tid == 0) offs[N] = carry + chunk_total;
    } else {
        // gemm1: h1 = bf16(x @ W1), UNSCALED (depends only on phase A's W1f)
        constexpr int K = 128, BN = 128;
        int lane = tid & 63;
        int w = tid >> 6;
        for (int g = b - SB; g < GB; g += NB - SB) {
            int row0 = g * 64;
            short8 bfr[2][4];
            #pragma unroll
            for (int nl = 0; nl < 2; nl++)
                #pragma unroll
                for (int ks = 0; ks < 4; ks++)
                    bfr[nl][ks] = *(const short8*)(W1f + ((((w * 2 + nl) * 4 + ks) * 64) + lane) * 8);

            #pragma unroll
            for (int it = 0; it < 8; it++) {
                int idx = it * 256 + tid;
                int row = idx >> 5, kq = idx & 31;
                int k0 = kq * 4;
                int ks = k0 >> 5, quad = (k0 >> 3) & 3, j0 = k0 & 7, mt = row >> 4;
                ushort4 o = make_ushort4(0, 0, 0, 0);
                int gr = row0 + row;
                if (gr < N) {
                    float4 a = *(const float4*)(x + (size_t)gr * K + k0);
                    o.x = f2bf(a.x); o.y = f2bf(a.y); o.z = f2bf(a.z); o.w = f2bf(a.w);
                }
                int off = (((mt * 4 + ks) * 64) + (row & 15) + 16 * quad) * 8 + j0;
                *(ushort4*)(As + off) = o;
            }
            __syncthreads();

            f32x4 acc[4][2];
            #pragma unroll
            for (int mt = 0; mt < 4; mt++)
                #pragma unroll
                for (int nl = 0; nl < 2; nl++) acc[mt][nl] = (f32x4){0.f, 0.f, 0.f, 0.f};

            #pragma unroll
            for (int ks = 0; ks < 4; ks++) {
                short8 af[4];
                #pragma unroll
                for (int mt = 0; mt < 4; mt++)
                    af[mt] = *(const short8*)(As + (((mt * 4 + ks) * 64) + lane) * 8);
                #pragma unroll
                for (int mt = 0; mt < 4; mt++)
                    #pragma unroll
                    for (int nl = 0; nl < 2; nl++)
                        acc[mt][nl] = __builtin_amdgcn_mfma_f32_16x16x32_bf16(
                            af[mt], bfr[nl][ks], acc[mt][nl], 0, 0, 0);
            }

            int col16 = lane & 15;
            int rowq = lane >> 4;
            #pragma unroll
            for (int mt = 0; mt < 4; mt++) {
                #pragma unroll
                for (int nl = 0; nl < 2; nl++) {
                    int gc = (w * 2 + nl) * 16 + col16;
                    #pragma unroll
                    for (int r = 0; r < 4; r++) {
                        int lr = mt * 16 + rowq * 4 + r;
                        int gr = row0 + lr;
                        if (gr < N) h1[(size_t)gr * BN + gc] = f2bf(acc[mt][nl][r]);
                    }
                }
            }
            __syncthreads();  // protect As before next grid-stride iteration
        }
    }
    grid.sync();

    // ================= D: fill (4 edges/thread, no atomics) ================
    for (int u = b; u < CB; u += NB) {
        int i = (u * 256 + tid) * 4;
        if (i + 3 < E) {
            int4 s4 = *(const int4*)(src + i);
            int4 d4 = *(const int4*)(dst + i);
            ushort4 r4 = *(const ushort4*)(rank + i);
            csr[offs[d4.x] + (int)r4.x] = s4.x;
            csr[offs[d4.y] + (int)r4.y] = s4.y;
            csr[offs[d4.z] + (int)r4.z] = s4.z;
            csr[offs[d4.w] + (int)r4.w] = s4.w;
        } else {
            for (; i < E; i++) csr[offs[dst[i]] + (int)rank[i]] = src[i];
        }
    }
    grid.sync();

    // ====== E: aggmm (Agg1 + bias + ReLU + GEMM2, dinv[s] edge weights) ====
    {
        int t = tid & 63;
        int w = tid >> 6;
        int p = t >> 5;
        int t5 = t & 31;
        for (int g = b; g < AT; g += NB) {
            int nodebase = g * 16;
            int node0 = nodebase + w * 4;

            int ov = offs[min(node0 + min(t, 4), N)];
            int e0a[4], dega[4], nba[4], cidx[4];
            float cdw[4], dia[4];
            #pragma unroll
            for (int i = 0; i < 4; i++) {
                e0a[i] = __shfl(ov, i, 64);
                dega[i] = __shfl(ov, i + 1, 64) - e0a[i];
                nba[i] = min(dega[i], 64);
                int ce = e0a[i] + min(t, max(dega[i] - 1, 0));
                bool has = dega[i] > 0;
                cidx[i] = has ? csr[ce] : 0;
                cdw[i] = has ? dinv[cidx[i]] : 0.f;
                int node = node0 + i;
                dia[i] = (node < N) ? dinv[node] : 0.f;
            }

            short8 bw[4];
            #pragma unroll
            for (int ks = 0; ks < 4; ks++)
                bw[ks] = *(const short8*)(W2f + (((w * 4 + ks) * 64) + t) * 8);

            float4 bias = *(const float4*)(b1 + t5 * 4);

            #pragma unroll
            for (int i = 0; i < 4; i++) {
                int row16 = w * 4 + i;
                int node = node0 + i;
                float a0 = 0.f, a1 = 0.f, a2 = 0.f, a3 = 0.f;
                if (node < N) {
                    if (p == 0) {  // self term x dinv[d]
                        uint2 su = *(const uint2*)(h1 + (size_t)node * 128 + t5 * 4);
                        a0 = bf2f_lo(su.x) * dia[i]; a1 = bf2f_hi(su.x) * dia[i];
                        a2 = bf2f_lo(su.y) * dia[i]; a3 = bf2f_hi(su.y) * dia[i];
                    }
                    for (int jb = 0; jb < nba[i]; jb += 8) {
                        #pragma unroll
                        for (int j = 0; j < 4; j++) {
                            int ee = jb + j * 2 + p;
                            int ec = min(ee, nba[i] - 1);
                            int s = __shfl(cidx[i], ec, 64);
                            float wraw = __shfl(cdw[i], ec, 64);
                            float wgt = (ee < nba[i]) ? wraw : 0.f;
                            uint2 hu = *(const uint2*)(h1 + (size_t)s * 128 + t5 * 4);
                            a0 += bf2f_lo(hu.x) * wgt; a1 += bf2f_hi(hu.x) * wgt;
                            a2 += bf2f_lo(hu.y) * wgt; a3 += bf2f_hi(hu.y) * wgt;
                        }
                    }
                    int e1 = e0a[i] + dega[i];
                    for (int eb = e0a[i] + 64; eb < e1; eb += 8) {
                        #pragma unroll
                        for (int j = 0; j < 4; j++) {
                            int ee = eb + j * 2 + p;
                            int ec = min(ee, e1 - 1);
                            int s = csr[ec];
                            float wgt = (ee < e1) ? dinv[s] : 0.f;
                            uint2 hu = *(const uint2*)(h1 + (size_t)s * 128 + t5 * 4);
                            a0 += bf2f_lo(hu.x) * wgt; a1 += bf2f_hi(hu.x) * wgt;
                            a2 += bf2f_lo(hu.y) * wgt; a3 += bf2f_hi(hu.y) * wgt;
                        }
                    }
                }
                a0 += __shfl_xor(a0, 32, 64);
                a1 += __shfl_xor(a1, 32, 64);
                a2 += __shfl_xor(a2, 32, 64);
                a3 += __shfl_xor(a3, 32, 64);
                if (p == 0) {
                    if (node < N) {
                        a0 = fmaxf(a0 * dia[i] + bias.x, 0.f);
                        a1 = fmaxf(a1 * dia[i] + bias.y, 0.f);
                        a2 = fmaxf(a2 * dia[i] + bias.z, 0.f);
                        a3 = fmaxf(a3 * dia[i] + bias.w, 0.f);
                    }
                    int k0 = t5 * 4;
                    int ks = k0 >> 5, quad = (k0 >> 3) & 3, j0 = k0 & 7;
                    ushort4 pk4 = make_ushort4(f2bf(a0), f2bf(a1), f2bf(a2), f2bf(a3));
                    *(ushort4*)(As + ((ks * 64) + row16 + 16 * quad) * 8 + j0) = pk4;
                }
            }
            __syncthreads();

            f32x4 acc = (f32x4){0.f, 0.f, 0.f, 0.f};
            #pragma unroll
            for (int ks = 0; ks < 4; ks++) {
                short8 af = *(const short8*)(As + ((ks * 64) + t) * 8);
                acc = __builtin_amdgcn_mfma_f32_16x16x32_bf16(af, bw[ks], acc, 0, 0, 0);
            }

            int col = w * 16 + (t & 15);
            int rowq = t >> 4;
            #pragma unroll
            for (int r = 0; r < 4; r++) {
                int gr = nodebase + rowq * 4 + r;
                if (gr < N) h2[(size_t)gr * 64 + col] = f2bf(acc[r] * dinv[gr]);
            }
            __syncthreads();  // protect As before next grid-stride iteration
        }
    }
    grid.sync();

    // ================= F: aggout (h2 pre-folded, unit weights) =============
    {
        int t = tid & 63;
        int w = tid >> 6;
        int p = t >> 4;
        int t4 = t & 15;
        for (int g = b; g < OT; g += NB) {
            int node = g * 4 + w;
            if (node < N) {
                int e0 = offs[node];
                int e1 = offs[node + 1];
                int dg = e1 - e0;
                int nb = min(dg, 64);
                int cidx = (dg > 0) ? csr[e0 + min(t, max(dg - 1, 0))] : 0;

                float a0 = 0.f, a1 = 0.f, a2 = 0.f, a3 = 0.f;
                float di = dinv[node];
                if (p == 0) {
                    uint2 su = *(const uint2*)(h2 + (size_t)node * 64 + t4 * 4);
                    a0 = bf2f_lo(su.x); a1 = bf2f_hi(su.x);
                    a2 = bf2f_lo(su.y); a3 = bf2f_hi(su.y);
                }

                for (int jb = 0; jb < nb; jb += 8) {
                    #pragma unroll
                    for (int j = 0; j < 2; j++) {
                        int ee = jb + j * 4 + p;
                        int ec = min(ee, nb - 1);
                        int s = __shfl(cidx, ec, 64);
                        float wgt = (ee < dg) ? 1.f : 0.f;
                        uint2 hu = *(const uint2*)(h2 + (size_t)s * 64 + t4 * 4);
                        a0 += bf2f_lo(hu.x) * wgt; a1 += bf2f_hi(hu.x) * wgt;
                        a2 += bf2f_lo(hu.y) * wgt; a3 += bf2f_hi(hu.y) * wgt;
                    }
                }
                for (int eb = e0 + 64; eb < e1; eb += 8) {
                    #pragma unroll
                    for (int j = 0; j < 2; j++) {
                        int ee = eb + j * 4 + p;
                        int ec = min(ee, e1 - 1);
                        int s = csr[ec];
                        float wgt = (ee < e1) ? 1.f : 0.f;
                        uint2 hu = *(const uint2*)(h2 + (size_t)s * 64 + t4 * 4);
                        a0 += bf2f_lo(hu.x) * wgt; a1 += bf2f_hi(hu.x) * wgt;
                        a2 += bf2f_lo(hu.y) * wgt; a3 += bf2f_hi(hu.y) * wgt;
                    }
                }
                a0 += __shfl_xor(a0, 16, 64); a1 += __shfl_xor(a1, 16, 64);
                a2 += __shfl_xor(a2, 16, 64); a3 += __shfl_xor(a3, 16, 64);
                a0 += __shfl_xor(a0, 32, 64); a1 += __shfl_xor(a1, 32, 64);
                a2 += __shfl_xor(a2, 32, 64); a3 += __shfl_xor(a3, 32, 64);
                if (p == 0) {
                    float4 bb = *(const float4*)(b2 + t4 * 4);
                    *(float4*)(out + (size_t)node * 64 + t4 * 4) =
                        make_float4(a0 * di + bb.x, a1 * di + bb.y,
                                    a2 * di + bb.z, a3 * di + bb.w);
                }
            }
        }
    }
}

extern "C" void kernel_launch(void* const* d_in, const int* in_sizes, int n_in,
                              void* d_out, int out_size, void* d_ws, size_t ws_size,
                              hipStream_t stream) {
    const float* x  = (const float*)d_in[0];
    const int*   ei = (const int*)d_in[1];
    const float* W1 = (const float*)d_in[2];
    const float* b1 = (const float*)d_in[3];
    const float* W2 = (const float*)d_in[4];
    const float* b2 = (const float*)d_in[5];

    int N = in_sizes[0] / 128;   // 50000
    int E = in_sizes[1] / 2;     // 500000
    const int* src = ei;
    const int* dst = ei + E;

    char* p = (char*)d_ws;
    auto alloc = [&](size_t bytes) {
        char* r = p;
        p += (bytes + 255) & ~(size_t)255;
        return r;
    };
    int*   degi  = (int*)  alloc((size_t)N * 4);
    float* dinv  = (float*)alloc((size_t)N * 4);
    int*   offs  = (int*)  alloc((size_t)(N + 1) * 4);
    u64*   lb    = (u64*)  alloc((size_t)64 * 8);
    unsigned short* rank = (unsigned short*)alloc((size_t)E * 2);
    int*            csr  = (int*)alloc((size_t)E * 4);
    unsigned short* W1f  = (unsigned short*)alloc((size_t)128 * 128 * 2);
    unsigned short* W2f  = (unsigned short*)alloc((size_t)64 * 128 * 2);
    unsigned short* h1   = (unsigned short*)alloc((size_t)N * 128 * 2);
    unsigned short* h2   = (unsigned short*)alloc((size_t)N * 64 * 2);
    float* out = (float*)d_out;

    int CB = (E / 4 + 255) / 256;  // 489
    int SB = (N + 1023) / 1024;    // 49
    int GB = (N + 63) / 64;        // 782
    int AT = (N + 15) / 16;        // 3125
    int OT = (N + 3) / 4;          // 12500

    int maxActive = 0;
    hipOccupancyMaxActiveBlocksPerMultiprocessor(&maxActive, fused_kernel, 256, 0);
    if (maxActive < 1) maxActive = 1;
    int NB = maxActive * 256;      // 256 CUs on MI355X
    if (NB > 2048) NB = 2048;

    void* args[] = { (void*)&src, (void*)&dst, (void*)&E,
                     (void*)&degi, (void*)&rank,
                     (void*)&W1, (void*)&W2, (void*)&W1f, (void*)&W2f,
                     (void*)&lb,
                     (void*)&x, (void*)&h1,
                     (void*)&offs, (void*)&dinv,
                     (void*)&csr,
                     (void*)&b1, (void*)&b2,
                     (void*)&h2, (void*)&out,
                     (void*)&N, (void*)&CB, (void*)&SB, (void*)&GB,
                     (void*)&AT, (void*)&OT };

    hipLaunchCooperativeKernel((void*)fused_kernel, dim3(NB), dim3(256),
                               args, 0, stream);
}